// Round 18
// baseline (124.431 us; speedup 1.0000x reference)
//
#include <hip/hip_runtime.h>
#include <hip/hip_bf16.h>
#include <math.h>

// LID_NSALoss: int8-MFMA candidate kNN. 16-wave blocks (BM=128, 1 block/CU),
// kb-unrolled jt-loop with named rotating buffers, 3-deep B prefetch with
// counted vmcnt + raw s_barrier. A-operand fragments hoisted to REGISTERS
// (jt-invariant -> 33% less LDS read traffic). Per-lane top-6 packed-key
// threshold filter in registers. Exact fp32 re-rank of quantized top-8 +
// LID loss. Quantile normalizers cancel in the log-ratios -> skipped.

#define NROWS 8192
#define DX 512
#define DZ 128
#define KNN 5
#define NSTRIP 4
#define SSPAN (NROWS / NSTRIP)   // 2048
#define BM 128                   // rows per block
#define BN 256                   // cols per j-tile
#define NJT (SSPAN / BN)         // 8
#define NCAND (NSTRIP * KNN)     // 20
#define QSCALE 30.0f

typedef int i32x4 __attribute__((ext_vector_type(4)));
typedef int i32x16 __attribute__((ext_vector_type(16)));

__device__ __forceinline__ bool ilexless(int d1, int i1, int d2, int i2) {
  return (d1 < d2) || (d1 == d2 && i1 < i2);
}
__device__ __forceinline__ bool flexless(float d1, int i1, float d2, int i2) {
  return (d1 < d2) || (d1 == d2 && i1 < i2);
}

// sorted inserts on packed keys (numeric order == (d,col) lex order)
__device__ __forceinline__ void ins5k(int k, int* md) {
  if (k >= md[4]) return;
  int nk = k;
#pragma unroll
  for (int p = 0; p < 5; ++p) {
    const bool sw = nk < md[p];
    const int tk = sw ? md[p] : nk;
    md[p] = sw ? nk : md[p];
    nk = tk;
  }
}
__device__ __forceinline__ void ins6k(int k, int* md) {
  if (k >= md[5]) return;
  int nk = k;
#pragma unroll
  for (int p = 0; p < 6; ++p) {
    const bool sw = nk < md[p];
    const int tk = sw ? md[p] : nk;
    md[p] = sw ? nk : md[p];
    nk = tk;
  }
}
__device__ __forceinline__ void ins8i(int d, int i, int* md, int* mi) {
  if (!ilexless(d, i, md[7], mi[7])) return;
  int nd = d, ni = i;
#pragma unroll
  for (int p = 0; p < 8; ++p) {
    const bool sw = ilexless(nd, ni, md[p], mi[p]);
    const int td = sw ? md[p] : nd; const int ti = sw ? mi[p] : ni;
    md[p] = sw ? nd : md[p]; mi[p] = sw ? ni : mi[p];
    nd = td; ni = ti;
  }
}
__device__ __forceinline__ void ins5f(float d, int i, float* md, int* mi) {
  if (!flexless(d, i, md[4], mi[4])) return;
  float nd = d; int ni = i;
#pragma unroll
  for (int p = 0; p < 5; ++p) {
    const bool sw = flexless(nd, ni, md[p], mi[p]);
    const float td = sw ? md[p] : nd; const int ti = sw ? mi[p] : ni;
    md[p] = sw ? nd : md[p]; mi[p] = sw ? ni : mi[p];
    nd = td; ni = ti;
  }
}

__device__ __forceinline__ void gload_lds16(const void* g, void* l) {
  __builtin_amdgcn_global_load_lds((const __attribute__((address_space(1))) void*)g,
                                   (__attribute__((address_space(3))) void*)l,
                                   16, 0, 0);
}

// --- fused: quantize X (+sqx,+sqq) | Z row norms (+sqz) ------------------
__global__ __launch_bounds__(256) void prep_kernel(const float* __restrict__ X,
                                                   const float* __restrict__ Z,
                                                   signed char* __restrict__ Xq,
                                                   float* __restrict__ sqx,
                                                   int* __restrict__ sqq,
                                                   float* __restrict__ sqz) {
  const int b = blockIdx.x;
  const int w = threadIdx.x >> 6;
  const int lane = threadIdx.x & 63;
  if (b < NROWS / 4) {
    const int row = (b << 2) + w;
    const float* p = X + (size_t)row * DX + lane * 8;
    const float4 v0 = *(const float4*)(p);
    const float4 v1 = *(const float4*)(p + 4);
    float xs[8] = {v0.x, v0.y, v0.z, v0.w, v1.x, v1.y, v1.z, v1.w};
    float s = 0.f;
    int q[8];
    int si = 0;
#pragma unroll
    for (int j = 0; j < 8; ++j) {
      s = fmaf(xs[j], xs[j], s);
      q[j] = (int)rintf(fminf(fmaxf(xs[j] * QSCALE, -127.f), 127.f));
      si += q[j] * q[j];
    }
    const int b0 = (q[0] & 255) | ((q[1] & 255) << 8) | ((q[2] & 255) << 16) | ((q[3] & 255) << 24);
    const int b1 = (q[4] & 255) | ((q[5] & 255) << 8) | ((q[6] & 255) << 16) | ((q[7] & 255) << 24);
    *(int2*)(Xq + (size_t)row * DX + lane * 8) = make_int2(b0, b1);
#pragma unroll
    for (int off = 32; off > 0; off >>= 1) {
      s += __shfl_down(s, off, 64);
      si += __shfl_down(si, off, 64);
    }
    if (lane == 0) { sqx[row] = s; sqq[row] = si; }
  } else {
    const int row = ((b - NROWS / 4) << 2) + w;
    const float* p = Z + (size_t)row * DZ;
    const float a = p[lane];
    const float c = p[64 + lane];
    float s = fmaf(a, a, c * c);
#pragma unroll
    for (int off = 32; off > 0; off >>= 1) s += __shfl_down(s, off, 64);
    if (lane == 0) sqz[row] = s;
  }
}

// --- moments of sqq (deterministic fixed-order reduction, 1 block) -------
__global__ __launch_bounds__(1024) void stats_kernel(const int* __restrict__ sqq,
                                                     float* __restrict__ stats) {
  __shared__ double sw[16], sw2[16];
  const int t = threadIdx.x;
  double s = 0.0, s2 = 0.0;
  for (int i = t; i < NROWS; i += 1024) {
    const double v = (double)sqq[i];
    s += v; s2 += v * v;
  }
#pragma unroll
  for (int off = 32; off > 0; off >>= 1) {
    s += __shfl_down(s, off, 64);
    s2 += __shfl_down(s2, off, 64);
  }
  if ((t & 63) == 0) { sw[t >> 6] = s; sw2[t >> 6] = s2; }
  __syncthreads();
  if (t < 16) {
    double v = sw[t], v2 = sw2[t];
#pragma unroll
    for (int off = 8; off > 0; off >>= 1) {
      v += __shfl_down(v, off, 64);
      v2 += __shfl_down(v2, off, 64);
    }
    if (t == 0) {
      const double mu = v / (double)NROWS;
      stats[0] = (float)mu;
      stats[1] = (float)(v2 / (double)NROWS - mu * mu);
    }
  }
}

// --- i8 MFMA Gram, 16 waves, A-frags in registers, reg top-6 filter ------
// Wave w: col quarter cq=w&3 (64 cols: 2 n-frags), row quarter rh=w>>2
// (32 rows: 1 m-frag). D = mfma(colfrag, rowfrag): lane&31 = our row.
// LDS (dynamic 122880B): A transit 64K | B 3 bufs x 16K = 48K | qs 8K.
// 1 block/CU, 16 waves (4/SIMD). A-operand: 16 i32x4 in VGPRs (jt-invariant).
__global__ __launch_bounds__(1024, 1) void knn_i8_kernel(const signed char* __restrict__ Xq,
                                                         const int* __restrict__ sqq,
                                                         const float* __restrict__ stats,
                                                         int* __restrict__ cand_i,
                                                         int* __restrict__ cand_m) {
  extern __shared__ __align__(16) char lds[];
  char* ldsA = lds;                          // 65536 (prologue transit only)
  char* ldsBb = lds + 65536;                 // 49152 (3 bufs x 16384)
  int* qs = (int*)(lds + 114688);            // 8192: sqq[J0 .. J0+2047]

  const int bid = blockIdx.x;
  const int strip = bid & 3;                 // XCD pair per strip
  const int rowchunk = bid >> 2;
  const int I0 = rowchunk * BM;
  const int J0 = strip * SSPAN;

  const int t = threadIdx.x;
  const int w = t >> 6;
  const int lane = t & 63;
  const int l31 = lane & 31, lh5 = lane >> 5;
  const int cq = w & 3, rh = w >> 2;

  // per-row threshold: tau = mu - 2.2*sqrt(var + 4*E[q^2]*sqq_row)
  const float mu = stats[0];
  const float var = stats[1];
  const int lr = (rh << 5) + l31;            // tile-local row 0..127
  const int tau = (int)(mu - 2.2f * sqrtf(var + (mu * 0.0078125f) * (float)sqq[I0 + lr]));
  const int taubase = tau - 262144;

  // ---- precomputed per-lane addresses (loop-invariant) ----
  const char* Aaddr = ldsA + (lh5 << 11) + (lr << 4);          // + kb*8192 + ktl*4096
  const char* Ba0 = ldsBb + (lh5 << 12) + (((cq << 6) + l31) << 4);  // + ktl*8192
  const char* Ba1 = Ba0 + 16384;
  const char* Ba2 = Ba0 + 32768;
  char* Da0 = ldsBb + ((w >> 2) << 12) + ((w & 3) << 10);
  char* Da1 = Da0 + 16384;
  char* Da2 = Da0 + 32768;
  const signed char* sj = Xq + (size_t)(J0 + ((w & 3) << 6) + lane) * DX + ((w >> 2) << 4);
  const int* qw = qs + (cq << 6) + (lh5 << 2);
  int colj = J0 + (cq << 6) + (lh5 << 2);    // + n*32 + cconst[reg] per value

  // ---- prologue: stage A + qs, drain, hoist A-frags to registers ----
#pragma unroll
  for (int i = 0; i < 4; ++i) {
    const int idx = (w << 2) + i;             // 0..63
    const int g = idx >> 1, half = idx & 1;
    gload_lds16(Xq + (size_t)(I0 + half * 64 + lane) * DX + (g << 4),
                ldsA + g * 2048 + half * 1024);
  }
  if (w < 8)
    gload_lds16((const char*)(sqq + J0) + (w << 10) + (lane << 4),
                (char*)qs + (w << 10));
  __syncthreads();                            // vmcnt(0)+lgkmcnt(0)+barrier: A, qs visible

  // issue B steps 0,1 (outstanding at loop entry: exactly these two)
  gload_lds16(sj, Da0);
  gload_lds16(sj + 64, Da1);

  i32x4 areg[16];                             // statically indexed -> VGPRs
#pragma unroll
  for (int kb = 0; kb < 8; ++kb)
#pragma unroll
    for (int ktl = 0; ktl < 2; ++ktl)
      areg[kb * 2 + ktl] = *(const i32x4*)(Aaddr + kb * 8192 + ktl * 4096);

  const i32x16 z16 = {0, 0, 0, 0, 0, 0, 0, 0, 0, 0, 0, 0, 0, 0, 0, 0};
  i32x16 acc[2];   // [n]
  int md6[6];
#pragma unroll
  for (int q = 0; q < 6; ++q) md6[q] = 0x7fffffff;

  for (int jt = 0; jt < NJT; ++jt) {
    const signed char* sj2 = sj + BN * DX;    // next jt's source base
#pragma unroll
    for (int kb = 0; kb < 8; ++kb) {
      // oldest in-flight stage must have landed; keep 1 in flight.
      if (kb < 7 || jt < NJT - 1) {
        asm volatile("s_waitcnt vmcnt(1)" ::: "memory");
      } else {
        asm volatile("s_waitcnt vmcnt(0)" ::: "memory");
      }
      __builtin_amdgcn_s_barrier();
      __builtin_amdgcn_sched_barrier(0);
      // stage step s+2 into class (kb+2)%3 (buf read at step s-1: safe post-barrier)
      char* D = (kb % 3 == 1) ? Da0 : (kb % 3 == 2) ? Da1 : Da2;
      if (kb <= 5) {
        gload_lds16(sj + (kb + 2) * 64, D);
      } else if (jt < NJT - 1) {
        gload_lds16(sj2 + (kb - 6) * 64, D);
      }
      if (kb == 0) { acc[0] = z16; acc[1] = z16; }
      const char* B = (kb % 3 == 0) ? Ba0 : (kb % 3 == 1) ? Ba1 : Ba2;
#pragma unroll
      for (int ktl = 0; ktl < 2; ++ktl) {
        const i32x4 ap0 = *(const i32x4*)(B + ktl * 8192);
        const i32x4 ap1 = *(const i32x4*)(B + ktl * 8192 + 512);
        const i32x4 bp = areg[kb * 2 + ktl];
        acc[0] = __builtin_amdgcn_mfma_i32_32x32x32_i8(ap0, bp, acc[0], 0, 0, 0);
        acc[1] = __builtin_amdgcn_mfma_i32_32x32x32_i8(ap1, bp, acc[1], 0, 0, 0);
      }
      if (kb == 7) {
#pragma unroll
        for (int n = 0; n < 2; ++n) {
          const i32x4 q0 = *(const i32x4*)(qw + n * 32);
          const i32x4 q1 = *(const i32x4*)(qw + n * 32 + 8);
          const i32x4 q2 = *(const i32x4*)(qw + n * 32 + 16);
          const i32x4 q3 = *(const i32x4*)(qw + n * 32 + 24);
#pragma unroll
          for (int reg = 0; reg < 16; ++reg) {
            const int qv = (reg < 4) ? q0[reg & 3] : (reg < 8) ? q1[reg & 3]
                         : (reg < 12) ? q2[reg & 3] : q3[reg & 3];
            const int d = qv - 2 * acc[n][reg];
            if (d < tau) {
              const int cconst = (reg & 3) + ((reg >> 2) << 3);   // compile-time
              const int col = colj + n * 32 + cconst;
              const int v = max(d - taubase, 0);   // self / deep clamp
              ins6k((v << 13) | col, md6);         // pure VALU, exec-masked
            }
          }
        }
      }
    }
    // rotate buffer classes (advance by 8 = 2 mod 3) + advance bases
    { const char* tmp = Ba2; Ba2 = Ba1; Ba1 = Ba0; Ba0 = tmp; }
    { char* tmp = Da2; Da2 = Da1; Da1 = Da0; Da0 = tmp; }
    sj = sj2; qw += BN; colj += BN;
  }

  __syncthreads();   // loop done before LDS reuse

  // ---- merge: 8 lane-lists of 6 per row -> exact top-5 (self dropped) ----
  int* pm = (int*)ldsBb;                      // [128][8][6] = 24KB
  {
    const int sub = (cq << 1) | lh5;          // 0..7
#pragma unroll
    for (int q = 0; q < 6; ++q) pm[(lr * 8 + sub) * 6 + q] = md6[q];
  }
  __syncthreads();
  if (t < BM) {
    int md[5];
#pragma unroll
    for (int q = 0; q < 5; ++q) md[q] = 0x7fffffff;
    const int rgg = I0 + t;
    for (int c = 0; c < 8; ++c)
#pragma unroll
      for (int q = 0; q < 6; ++q) {
        const int key = pm[(t * 8 + c) * 6 + q];
        if ((key & 8191) != rgg) ins5k(key, md);   // drop self
      }
    const size_t base = (size_t)(I0 + t) * NCAND + strip * KNN;
#pragma unroll
    for (int q = 0; q < 5; ++q) {
      cand_m[base + q] = md[q];
      cand_i[base + q] = (md[q] == 0x7fffffff) ? 0x7fffffff : (md[q] & 8191);
    }
  }
}

// --- merge 20 packed candidates -> top-8 -> exact fp32 re-rank + LID -----
__global__ __launch_bounds__(256) void rerank_kernel(const float* __restrict__ X,
                                                     const float* __restrict__ Z,
                                                     const float* __restrict__ sqx,
                                                     const float* __restrict__ sqz,
                                                     const int* __restrict__ cand_i,
                                                     const int* __restrict__ cand_m,
                                                     float* __restrict__ row_out) {
  __shared__ float xrow[4][DX];
  const int w = threadIdx.x >> 6;
  const int lane = threadIdx.x & 63;
  const int row = (blockIdx.x << 2) + w;

  const float* xp = X + (size_t)row * DX + lane * 8;
  *(float4*)&xrow[w][lane * 8] = *(const float4*)(xp);
  *(float4*)&xrow[w][lane * 8 + 4] = *(const float4*)(xp + 4);

  int cm = 0x7fffffff, ci = 0x7fffffff;
  if (lane < NCAND) {
    cm = cand_m[(size_t)row * NCAND + lane];
    ci = cand_i[(size_t)row * NCAND + lane];
  }
  __syncthreads();

  int m8[8], i8v[8];
#pragma unroll
  for (int q = 0; q < 8; ++q) { m8[q] = 0x7fffffff; i8v[q] = 0x7fffffff; }
#pragma unroll
  for (int c = 0; c < NCAND; ++c) {
    const int dm = __shfl(cm, c, 64);
    const int di = __shfl(ci, c, 64);
    ins8i(dm, di, m8, i8v);
  }

  const int cgrp = lane >> 3, sgi = lane & 7;
  int j = (cgrp == 0) ? i8v[0] : (cgrp == 1) ? i8v[1] : (cgrp == 2) ? i8v[2] :
          (cgrp == 3) ? i8v[3] : (cgrp == 4) ? i8v[4] : (cgrp == 5) ? i8v[5] :
          (cgrp == 6) ? i8v[6] : i8v[7];
  if ((unsigned)j >= NROWS) j = 0;          // sentinel guard (P~0)
  const float* yp = X + (size_t)j * DX + sgi * 64;
  const float* xq_ = &xrow[w][sgi * 64];
  float dot = 0.f;
#pragma unroll 8
  for (int k = 0; k < 64; k += 4) {
    const float4 xv = *(const float4*)(xq_ + k);
    const float4 yv = *(const float4*)(yp + k);
    dot = fmaf(xv.x, yv.x, dot);
    dot = fmaf(xv.y, yv.y, dot);
    dot = fmaf(xv.z, yv.z, dot);
    dot = fmaf(xv.w, yv.w, dot);
  }
  dot += __shfl_xor(dot, 1, 64);
  dot += __shfl_xor(dot, 2, 64);
  dot += __shfl_xor(dot, 4, 64);
  const float d2 = sqx[row] + sqx[j] - 2.f * dot;

  float fd[5]; int fi[5];
#pragma unroll
  for (int q = 0; q < 5; ++q) { fd[q] = INFINITY; fi[q] = 0x7fffffff; }
#pragma unroll
  for (int cc = 0; cc < 8; ++cc) {
    const float dd = __shfl(d2, cc * 8, 64);
    if (lane == 0) ins5f(dd, i8v[cc], fd, fi);
  }
  float lidX = 0.f;
  if (lane == 0) {
    const float v4 = sqrtf(fmaxf(fd[4], 1e-12f)) + 1e-7f;
    const float l4 = log10f(v4);
#pragma unroll
    for (int q = 0; q < 5; ++q) {
      const float v = sqrtf(fmaxf(fd[q], 1e-12f)) + 1e-7f;
      lidX += log10f(v) - l4;
    }
  }
  int nb[5];
#pragma unroll
  for (int q = 0; q < 5; ++q) {
    nb[q] = __shfl(fi[q], 0, 64);
    if ((unsigned)nb[q] >= NROWS) nb[q] = 0;
  }

  const float zi0 = Z[(size_t)row * DZ + lane];
  const float zi1 = Z[(size_t)row * DZ + 64 + lane];
  float ez[5];
#pragma unroll
  for (int q = 0; q < 5; ++q) {
    const float* zn = Z + (size_t)nb[q] * DZ;
    float p = fmaf(zi0, zn[lane], zi1 * zn[64 + lane]);
#pragma unroll
    for (int off = 32; off > 0; off >>= 1) p += __shfl_down(p, off, 64);
    ez[q] = p;
  }
  if (lane == 0) {
    const float sqzr = sqz[row];
    float e[5];
    float mx = -INFINITY;
#pragma unroll
    for (int q = 0; q < 5; ++q) {
      const float d2z = sqzr + sqz[nb[q]] - 2.f * ez[q];
      e[q] = sqrtf(fmaxf(d2z, 1e-12f)) + 1e-7f;
      mx = fmaxf(mx, e[q]);
    }
    const float lmx = log10f(mx);
    float lidZ = 0.f;
#pragma unroll
    for (int q = 0; q < 5; ++q) lidZ += log10f(e[q]) - lmx;
    const float diff = 5.0f / (lidX + 1e-7f) - 5.0f / (lidZ + 1e-7f);
    row_out[row] = diff * diff;
  }
}

// --- final deterministic reduction --------------------------------------
__global__ __launch_bounds__(1024) void reduce_kernel(const float* __restrict__ row_out,
                                                      float* __restrict__ out) {
  __shared__ float sw[16];
  const int t = threadIdx.x;
  float s = 0.f;
  for (int i = t; i < NROWS; i += 1024) s += row_out[i];
#pragma unroll
  for (int off = 32; off > 0; off >>= 1) s += __shfl_down(s, off, 64);
  if ((t & 63) == 0) sw[t >> 6] = s;
  __syncthreads();
  if (t < 16) {
    float v = sw[t];
#pragma unroll
    for (int off = 8; off > 0; off >>= 1) v += __shfl_down(v, off, 64);
    if (t == 0) out[0] = v * (1.0f / (8192.0f * 25.0f));
  }
}

extern "C" void kernel_launch(void* const* d_in, const int* in_sizes, int n_in,
                              void* d_out, int out_size, void* d_ws, size_t ws_size,
                              hipStream_t stream) {
  const float* X = (const float*)d_in[0];
  const float* Z = (const float*)d_in[1];
  float* out = (float*)d_out;

  char* wb = (char*)d_ws;
  signed char* Xq = (signed char*)wb;                              // 4 MB
  float* sqx = (float*)(wb + (size_t)NROWS * DX);                  // 32 KB
  int* sqq = (int*)(sqx + NROWS);                                  // 32 KB
  float* sqz = (float*)(sqq + NROWS);                              // 32 KB
  int* cand_i = (int*)(sqz + NROWS);                               // 640 KB
  int* cand_m = cand_i + (size_t)NROWS * NCAND;                    // 640 KB
  float* row_out = (float*)(cand_m + (size_t)NROWS * NCAND);       // 32 KB
  float* stats = row_out + NROWS;                                  // 8 B

  prep_kernel<<<NROWS / 2, 256, 0, stream>>>(X, Z, Xq, sqx, sqq, sqz);
  stats_kernel<<<1, 1024, 0, stream>>>(sqq, stats);
  knn_i8_kernel<<<NSTRIP * (NROWS / BM), 1024, 122880, stream>>>(Xq, sqq, stats, cand_i, cand_m);
  rerank_kernel<<<NROWS / 4, 256, 0, stream>>>(X, Z, sqx, sqz, cand_i, cand_m, row_out);
  reduce_kernel<<<1, 1024, 0, stream>>>(row_out, out);
}

// Round 19
// 113.791 us; speedup vs baseline: 1.0935x; 1.0935x over previous
//
#include <hip/hip_runtime.h>
#include <hip/hip_bf16.h>
#include <math.h>

// LID_NSALoss: int8-MFMA candidate kNN. 16-wave blocks (BM=128, 1 block/CU),
// kb-unrolled jt-loop with named rotating buffers, 3-deep B prefetch with
// counted vmcnt + raw s_barrier. Strip-local moments computed in-kernel from
// the qs LDS strip (stats_kernel deleted); per-lane top-6 packed keys with
// raw-metric unpack at write-out (strip-independent cross-strip merge).
// Exact fp32 re-rank of quantized top-8 + LID loss. Quantile normalizers
// cancel in the log-ratios -> skipped.

#define NROWS 8192
#define DX 512
#define DZ 128
#define KNN 5
#define NSTRIP 4
#define SSPAN (NROWS / NSTRIP)   // 2048
#define BM 128                   // rows per block
#define BN 256                   // cols per j-tile
#define NJT (SSPAN / BN)         // 8
#define NCAND (NSTRIP * KNN)     // 20
#define QSCALE 30.0f

typedef int i32x4 __attribute__((ext_vector_type(4)));
typedef int i32x16 __attribute__((ext_vector_type(16)));

__device__ __forceinline__ bool ilexless(int d1, int i1, int d2, int i2) {
  return (d1 < d2) || (d1 == d2 && i1 < i2);
}
__device__ __forceinline__ bool flexless(float d1, int i1, float d2, int i2) {
  return (d1 < d2) || (d1 == d2 && i1 < i2);
}

// sorted inserts on packed keys (numeric order == (d,col) lex order)
__device__ __forceinline__ void ins5k(int k, int* md) {
  if (k >= md[4]) return;
  int nk = k;
#pragma unroll
  for (int p = 0; p < 5; ++p) {
    const bool sw = nk < md[p];
    const int tk = sw ? md[p] : nk;
    md[p] = sw ? nk : md[p];
    nk = tk;
  }
}
__device__ __forceinline__ void ins6k(int k, int* md) {
  if (k >= md[5]) return;
  int nk = k;
#pragma unroll
  for (int p = 0; p < 6; ++p) {
    const bool sw = nk < md[p];
    const int tk = sw ? md[p] : nk;
    md[p] = sw ? nk : md[p];
    nk = tk;
  }
}
__device__ __forceinline__ void ins8i(int d, int i, int* md, int* mi) {
  if (!ilexless(d, i, md[7], mi[7])) return;
  int nd = d, ni = i;
#pragma unroll
  for (int p = 0; p < 8; ++p) {
    const bool sw = ilexless(nd, ni, md[p], mi[p]);
    const int td = sw ? md[p] : nd; const int ti = sw ? mi[p] : ni;
    md[p] = sw ? nd : md[p]; mi[p] = sw ? ni : mi[p];
    nd = td; ni = ti;
  }
}
__device__ __forceinline__ void ins5f(float d, int i, float* md, int* mi) {
  if (!flexless(d, i, md[4], mi[4])) return;
  float nd = d; int ni = i;
#pragma unroll
  for (int p = 0; p < 5; ++p) {
    const bool sw = flexless(nd, ni, md[p], mi[p]);
    const float td = sw ? md[p] : nd; const int ti = sw ? mi[p] : ni;
    md[p] = sw ? nd : md[p]; mi[p] = sw ? ni : mi[p];
    nd = td; ni = ti;
  }
}

__device__ __forceinline__ void gload_lds16(const void* g, void* l) {
  __builtin_amdgcn_global_load_lds((const __attribute__((address_space(1))) void*)g,
                                   (__attribute__((address_space(3))) void*)l,
                                   16, 0, 0);
}

// --- fused: quantize X (+sqx,+sqq) | Z row norms (+sqz) ------------------
__global__ __launch_bounds__(256) void prep_kernel(const float* __restrict__ X,
                                                   const float* __restrict__ Z,
                                                   signed char* __restrict__ Xq,
                                                   float* __restrict__ sqx,
                                                   int* __restrict__ sqq,
                                                   float* __restrict__ sqz) {
  const int b = blockIdx.x;
  const int w = threadIdx.x >> 6;
  const int lane = threadIdx.x & 63;
  if (b < NROWS / 4) {
    const int row = (b << 2) + w;
    const float* p = X + (size_t)row * DX + lane * 8;
    const float4 v0 = *(const float4*)(p);
    const float4 v1 = *(const float4*)(p + 4);
    float xs[8] = {v0.x, v0.y, v0.z, v0.w, v1.x, v1.y, v1.z, v1.w};
    float s = 0.f;
    int q[8];
    int si = 0;
#pragma unroll
    for (int j = 0; j < 8; ++j) {
      s = fmaf(xs[j], xs[j], s);
      q[j] = (int)rintf(fminf(fmaxf(xs[j] * QSCALE, -127.f), 127.f));
      si += q[j] * q[j];
    }
    const int b0 = (q[0] & 255) | ((q[1] & 255) << 8) | ((q[2] & 255) << 16) | ((q[3] & 255) << 24);
    const int b1 = (q[4] & 255) | ((q[5] & 255) << 8) | ((q[6] & 255) << 16) | ((q[7] & 255) << 24);
    *(int2*)(Xq + (size_t)row * DX + lane * 8) = make_int2(b0, b1);
#pragma unroll
    for (int off = 32; off > 0; off >>= 1) {
      s += __shfl_down(s, off, 64);
      si += __shfl_down(si, off, 64);
    }
    if (lane == 0) { sqx[row] = s; sqq[row] = si; }
  } else {
    const int row = ((b - NROWS / 4) << 2) + w;
    const float* p = Z + (size_t)row * DZ;
    const float a = p[lane];
    const float c = p[64 + lane];
    float s = fmaf(a, a, c * c);
#pragma unroll
    for (int off = 32; off > 0; off >>= 1) s += __shfl_down(s, off, 64);
    if (lane == 0) sqz[row] = s;
  }
}

// --- i8 MFMA Gram, 16 waves, kb-unrolled, strip-local stats, filter ------
// Wave w: col quarter cq=w&3 (64 cols: 2 n-frags), row quarter rh=w>>2
// (32 rows: 1 m-frag). D = mfma(colfrag, rowfrag): lane&31 = our row.
// LDS (dynamic 123008B): A [32g][128r]x16B 64K | B 3 bufs x 16K = 48K |
// qs 8K | red 128B. 1 block/CU, 16 waves (4/SIMD).
__global__ __launch_bounds__(1024, 1) void knn_i8_kernel(const signed char* __restrict__ Xq,
                                                         const int* __restrict__ sqq,
                                                         int* __restrict__ cand_i,
                                                         int* __restrict__ cand_m) {
  extern __shared__ __align__(16) char lds[];
  char* ldsA = lds;                          // 65536
  char* ldsBb = lds + 65536;                 // 49152 (3 bufs x 16384)
  int* qs = (int*)(lds + 114688);            // 8192: sqq[J0 .. J0+2047]
  float* red = (float*)(lds + 122880);       // 32 floats (stats scratch)

  const int bid = blockIdx.x;
  const int strip = bid & 3;                 // XCD pair per strip
  const int rowchunk = bid >> 2;
  const int I0 = rowchunk * BM;
  const int J0 = strip * SSPAN;

  const int t = threadIdx.x;
  const int w = t >> 6;
  const int lane = t & 63;
  const int l31 = lane & 31, lh5 = lane >> 5;
  const int cq = w & 3, rh = w >> 2;
  const int lr = (rh << 5) + l31;            // tile-local row 0..127

  // ---- precomputed per-lane addresses (loop-invariant) ----
  const char* Aaddr = ldsA + (lh5 << 11) + (lr << 4);          // + kb*8192 + ktl*4096
  const char* Ba0 = ldsBb + (lh5 << 12) + (((cq << 6) + l31) << 4);  // + ktl*8192
  const char* Ba1 = Ba0 + 16384;
  const char* Ba2 = Ba0 + 32768;
  char* Da0 = ldsBb + ((w >> 2) << 12) + ((w & 3) << 10);
  char* Da1 = Da0 + 16384;
  char* Da2 = Da0 + 32768;
  const signed char* sj = Xq + (size_t)(J0 + ((w & 3) << 6) + lane) * DX + ((w >> 2) << 4);
  const int* qw = qs + (cq << 6) + (lh5 << 2);
  int colj = J0 + (cq << 6) + (lh5 << 2);    // + n*32 + cconst[reg] per value

  // ---- prologue: stage A + qs, drain, compute strip stats ----
#pragma unroll
  for (int i = 0; i < 4; ++i) {
    const int idx = (w << 2) + i;             // 0..63
    const int g = idx >> 1, half = idx & 1;
    gload_lds16(Xq + (size_t)(I0 + half * 64 + lane) * DX + (g << 4),
                ldsA + g * 2048 + half * 1024);
  }
  if (w < 8)
    gload_lds16((const char*)(sqq + J0) + (w << 10) + (lane << 4),
                (char*)qs + (w << 10));
  asm volatile("s_waitcnt vmcnt(0)" ::: "memory");
  __builtin_amdgcn_s_barrier();              // A + qs visible to all waves

  // strip-local moments (fixed-order float reduction -> deterministic,
  // identical for every block of this strip)
  {
    float s1, s2f;
    {
      const float v0 = (float)qs[t];
      const float v1 = (float)qs[t + 1024];
      s1 = v0 + v1;
      s2f = fmaf(v0, v0, v1 * v1);
    }
#pragma unroll
    for (int off = 32; off > 0; off >>= 1) {
      s1 += __shfl_down(s1, off, 64);
      s2f += __shfl_down(s2f, off, 64);
    }
    if (lane == 0) { red[w] = s1; red[16 + w] = s2f; }
  }
  __builtin_amdgcn_s_barrier();
  float S1 = 0.f, S2 = 0.f;
#pragma unroll
  for (int i = 0; i < 16; ++i) { S1 += red[i]; S2 += red[16 + i]; }
  const float mu = S1 * (1.0f / 2048.0f);
  const float var = S2 * (1.0f / 2048.0f) - mu * mu;
  // per-row threshold: tau = mu - 2.2*sqrt(var + 4*E[q^2]*sqq_row)
  const int tau = (int)(mu - 2.2f * sqrtf(var + (mu * 0.0078125f) * (float)sqq[I0 + lr]));
  const int taubase = tau - 262144;

  // issue B steps 0,1 (exactly these outstanding at loop entry)
  gload_lds16(sj, Da0);
  gload_lds16(sj + 64, Da1);

  const i32x16 z16 = {0, 0, 0, 0, 0, 0, 0, 0, 0, 0, 0, 0, 0, 0, 0, 0};
  i32x16 acc[2];   // [n]
  int md6[6];
#pragma unroll
  for (int q = 0; q < 6; ++q) md6[q] = 0x7fffffff;

  for (int jt = 0; jt < NJT; ++jt) {
    const signed char* sj2 = sj + BN * DX;    // next jt's source base
#pragma unroll
    for (int kb = 0; kb < 8; ++kb) {
      // oldest in-flight stage must have landed; keep 1 in flight.
      if (kb < 7 || jt < NJT - 1) {
        asm volatile("s_waitcnt vmcnt(1)" ::: "memory");
      } else {
        asm volatile("s_waitcnt vmcnt(0)" ::: "memory");
      }
      __builtin_amdgcn_s_barrier();
      __builtin_amdgcn_sched_barrier(0);
      // stage step s+2 into class (kb+2)%3 (buf read at step s-1: safe post-barrier)
      char* D = (kb % 3 == 1) ? Da0 : (kb % 3 == 2) ? Da1 : Da2;
      if (kb <= 5) {
        gload_lds16(sj + (kb + 2) * 64, D);
      } else if (jt < NJT - 1) {
        gload_lds16(sj2 + (kb - 6) * 64, D);
      }
      if (kb == 0) { acc[0] = z16; acc[1] = z16; }
      const char* B = (kb % 3 == 0) ? Ba0 : (kb % 3 == 1) ? Ba1 : Ba2;
#pragma unroll
      for (int ktl = 0; ktl < 2; ++ktl) {
        const i32x4 ap0 = *(const i32x4*)(B + ktl * 8192);
        const i32x4 ap1 = *(const i32x4*)(B + ktl * 8192 + 512);
        const i32x4 bp = *(const i32x4*)(Aaddr + kb * 8192 + ktl * 4096);
        acc[0] = __builtin_amdgcn_mfma_i32_32x32x32_i8(ap0, bp, acc[0], 0, 0, 0);
        acc[1] = __builtin_amdgcn_mfma_i32_32x32x32_i8(ap1, bp, acc[1], 0, 0, 0);
      }
      if (kb == 7) {
#pragma unroll
        for (int n = 0; n < 2; ++n) {
          const i32x4 q0 = *(const i32x4*)(qw + n * 32);
          const i32x4 q1 = *(const i32x4*)(qw + n * 32 + 8);
          const i32x4 q2 = *(const i32x4*)(qw + n * 32 + 16);
          const i32x4 q3 = *(const i32x4*)(qw + n * 32 + 24);
#pragma unroll
          for (int reg = 0; reg < 16; ++reg) {
            const int qv = (reg < 4) ? q0[reg & 3] : (reg < 8) ? q1[reg & 3]
                         : (reg < 12) ? q2[reg & 3] : q3[reg & 3];
            const int d = qv - 2 * acc[n][reg];
            if (d < tau) {
              const int cconst = (reg & 3) + ((reg >> 2) << 3);   // compile-time
              const int col = colj + n * 32 + cconst;
              const int v = max(d - taubase, 0);   // self / deep clamp
              ins6k((v << 13) | col, md6);         // pure VALU, exec-masked
            }
          }
        }
      }
    }
    // rotate buffer classes (advance by 8 = 2 mod 3) + advance bases
    { const char* tmp = Ba2; Ba2 = Ba1; Ba1 = Ba0; Ba0 = tmp; }
    { char* tmp = Da2; Da2 = Da1; Da1 = Da0; Da0 = tmp; }
    sj = sj2; qw += BN; colj += BN;
  }

  __syncthreads();   // loop done before LDS reuse

  // ---- merge: 8 lane-lists of 6 per row -> exact top-5 (self dropped) ----
  int* pm = (int*)ldsBb;                      // [128][8][6] = 24KB
  {
    const int sub = (cq << 1) | lh5;          // 0..7
#pragma unroll
    for (int q = 0; q < 6; ++q) pm[(lr * 8 + sub) * 6 + q] = md6[q];
  }
  __syncthreads();
  if (t < BM) {
    int md[5];
#pragma unroll
    for (int q = 0; q < 5; ++q) md[q] = 0x7fffffff;
    const int rgg = I0 + t;
    for (int c = 0; c < 8; ++c)
#pragma unroll
      for (int q = 0; q < 6; ++q) {
        const int key = pm[(t * 8 + c) * 6 + q];
        if ((key & 8191) != rgg) ins5k(key, md);   // drop self
      }
    // recompute this row's taubase (same formula/order as filter -> bit-equal)
    const int taur = (int)(mu - 2.2f * sqrtf(var + (mu * 0.0078125f) * (float)sqq[rgg]));
    const int tbr = taur - 262144;
    const size_t base = (size_t)(I0 + t) * NCAND + strip * KNN;
#pragma unroll
    for (int q = 0; q < 5; ++q) {
      // unpack to RAW quantized metric (strip-independent for cross-strip merge)
      cand_m[base + q] = (md[q] == 0x7fffffff) ? 0x7fffffff : ((md[q] >> 13) + tbr);
      cand_i[base + q] = (md[q] == 0x7fffffff) ? 0x7fffffff : (md[q] & 8191);
    }
  }
}

// --- merge 20 raw-metric candidates -> top-8 -> exact fp32 re-rank + LID -
__global__ __launch_bounds__(256) void rerank_kernel(const float* __restrict__ X,
                                                     const float* __restrict__ Z,
                                                     const float* __restrict__ sqx,
                                                     const float* __restrict__ sqz,
                                                     const int* __restrict__ cand_i,
                                                     const int* __restrict__ cand_m,
                                                     float* __restrict__ row_out) {
  __shared__ float xrow[4][DX];
  const int w = threadIdx.x >> 6;
  const int lane = threadIdx.x & 63;
  const int row = (blockIdx.x << 2) + w;

  const float* xp = X + (size_t)row * DX + lane * 8;
  *(float4*)&xrow[w][lane * 8] = *(const float4*)(xp);
  *(float4*)&xrow[w][lane * 8 + 4] = *(const float4*)(xp + 4);

  int cm = 0x7fffffff, ci = 0x7fffffff;
  if (lane < NCAND) {
    cm = cand_m[(size_t)row * NCAND + lane];
    ci = cand_i[(size_t)row * NCAND + lane];
  }
  __syncthreads();

  int m8[8], i8v[8];
#pragma unroll
  for (int q = 0; q < 8; ++q) { m8[q] = 0x7fffffff; i8v[q] = 0x7fffffff; }
#pragma unroll
  for (int c = 0; c < NCAND; ++c) {
    const int dm = __shfl(cm, c, 64);
    const int di = __shfl(ci, c, 64);
    ins8i(dm, di, m8, i8v);
  }

  const int cgrp = lane >> 3, sgi = lane & 7;
  int j = (cgrp == 0) ? i8v[0] : (cgrp == 1) ? i8v[1] : (cgrp == 2) ? i8v[2] :
          (cgrp == 3) ? i8v[3] : (cgrp == 4) ? i8v[4] : (cgrp == 5) ? i8v[5] :
          (cgrp == 6) ? i8v[6] : i8v[7];
  if ((unsigned)j >= NROWS) j = 0;          // sentinel guard (P~0)
  const float* yp = X + (size_t)j * DX + sgi * 64;
  const float* xq_ = &xrow[w][sgi * 64];
  float dot = 0.f;
#pragma unroll 8
  for (int k = 0; k < 64; k += 4) {
    const float4 xv = *(const float4*)(xq_ + k);
    const float4 yv = *(const float4*)(yp + k);
    dot = fmaf(xv.x, yv.x, dot);
    dot = fmaf(xv.y, yv.y, dot);
    dot = fmaf(xv.z, yv.z, dot);
    dot = fmaf(xv.w, yv.w, dot);
  }
  dot += __shfl_xor(dot, 1, 64);
  dot += __shfl_xor(dot, 2, 64);
  dot += __shfl_xor(dot, 4, 64);
  const float d2 = sqx[row] + sqx[j] - 2.f * dot;

  float fd[5]; int fi[5];
#pragma unroll
  for (int q = 0; q < 5; ++q) { fd[q] = INFINITY; fi[q] = 0x7fffffff; }
#pragma unroll
  for (int cc = 0; cc < 8; ++cc) {
    const float dd = __shfl(d2, cc * 8, 64);
    if (lane == 0) ins5f(dd, i8v[cc], fd, fi);
  }
  float lidX = 0.f;
  if (lane == 0) {
    const float v4 = sqrtf(fmaxf(fd[4], 1e-12f)) + 1e-7f;
    const float l4 = log10f(v4);
#pragma unroll
    for (int q = 0; q < 5; ++q) {
      const float v = sqrtf(fmaxf(fd[q], 1e-12f)) + 1e-7f;
      lidX += log10f(v) - l4;
    }
  }
  int nb[5];
#pragma unroll
  for (int q = 0; q < 5; ++q) {
    nb[q] = __shfl(fi[q], 0, 64);
    if ((unsigned)nb[q] >= NROWS) nb[q] = 0;
  }

  const float zi0 = Z[(size_t)row * DZ + lane];
  const float zi1 = Z[(size_t)row * DZ + 64 + lane];
  float ez[5];
#pragma unroll
  for (int q = 0; q < 5; ++q) {
    const float* zn = Z + (size_t)nb[q] * DZ;
    float p = fmaf(zi0, zn[lane], zi1 * zn[64 + lane]);
#pragma unroll
    for (int off = 32; off > 0; off >>= 1) p += __shfl_down(p, off, 64);
    ez[q] = p;
  }
  if (lane == 0) {
    const float sqzr = sqz[row];
    float e[5];
    float mx = -INFINITY;
#pragma unroll
    for (int q = 0; q < 5; ++q) {
      const float d2z = sqzr + sqz[nb[q]] - 2.f * ez[q];
      e[q] = sqrtf(fmaxf(d2z, 1e-12f)) + 1e-7f;
      mx = fmaxf(mx, e[q]);
    }
    const float lmx = log10f(mx);
    float lidZ = 0.f;
#pragma unroll
    for (int q = 0; q < 5; ++q) lidZ += log10f(e[q]) - lmx;
    const float diff = 5.0f / (lidX + 1e-7f) - 5.0f / (lidZ + 1e-7f);
    row_out[row] = diff * diff;
  }
}

// --- final deterministic reduction --------------------------------------
__global__ __launch_bounds__(1024) void reduce_kernel(const float* __restrict__ row_out,
                                                      float* __restrict__ out) {
  __shared__ float sw[16];
  const int t = threadIdx.x;
  float s = 0.f;
  for (int i = t; i < NROWS; i += 1024) s += row_out[i];
#pragma unroll
  for (int off = 32; off > 0; off >>= 1) s += __shfl_down(s, off, 64);
  if ((t & 63) == 0) sw[t >> 6] = s;
  __syncthreads();
  if (t < 16) {
    float v = sw[t];
#pragma unroll
    for (int off = 8; off > 0; off >>= 1) v += __shfl_down(v, off, 64);
    if (t == 0) out[0] = v * (1.0f / (8192.0f * 25.0f));
  }
}

extern "C" void kernel_launch(void* const* d_in, const int* in_sizes, int n_in,
                              void* d_out, int out_size, void* d_ws, size_t ws_size,
                              hipStream_t stream) {
  const float* X = (const float*)d_in[0];
  const float* Z = (const float*)d_in[1];
  float* out = (float*)d_out;

  char* wb = (char*)d_ws;
  signed char* Xq = (signed char*)wb;                              // 4 MB
  float* sqx = (float*)(wb + (size_t)NROWS * DX);                  // 32 KB
  int* sqq = (int*)(sqx + NROWS);                                  // 32 KB
  float* sqz = (float*)(sqq + NROWS);                              // 32 KB
  int* cand_i = (int*)(sqz + NROWS);                               // 640 KB
  int* cand_m = cand_i + (size_t)NROWS * NCAND;                    // 640 KB
  float* row_out = (float*)(cand_m + (size_t)NROWS * NCAND);       // 32 KB

  prep_kernel<<<NROWS / 2, 256, 0, stream>>>(X, Z, Xq, sqx, sqq, sqz);
  knn_i8_kernel<<<NSTRIP * (NROWS / BM), 1024, 123008, stream>>>(Xq, sqq, cand_i, cand_m);
  rerank_kernel<<<NROWS / 4, 256, 0, stream>>>(X, Z, sqx, sqz, cand_i, cand_m, row_out);
  reduce_kernel<<<1, 1024, 0, stream>>>(row_out, out);
}